// Round 3
// baseline (199.320 us; speedup 1.0000x reference)
//
#include <hip/hip_runtime.h>

#define B_  8
#define LV_ 4096
#define D_  256
#define N_  2048
#define P_  32

typedef float v4f __attribute__((ext_vector_type(4)));

__device__ __forceinline__ float lane_bcast_f(float v, int l) {
    return __int_as_float(__builtin_amdgcn_readlane(__float_as_int(v), l));
}

// Pass 1: counting-sort box ids by batch into order[] (d_ws) for XCD-L2 locality.
__global__ __launch_bounds__(256) void build_order_kernel(
    const int* __restrict__ batch_idx, int* __restrict__ order)
{
    __shared__ int cnt[B_], cur[B_];
    const int tid = threadIdx.x;
    if (tid < B_) cnt[tid] = 0;
    __syncthreads();
    for (int n = tid; n < N_; n += 256) atomicAdd(&cnt[batch_idx[n]], 1);
    __syncthreads();
    if (tid == 0) {
        int s = 0;
        for (int b = 0; b < B_; ++b) { cur[b] = s; s += cnt[b]; }
    }
    __syncthreads();
    for (int n = tid; n < N_; n += 256)
        order[atomicAdd(&cur[batch_idx[n]], 1)] = n;
}

// Pass 2: one wave per (box, bin), 4 waves per block.
//
// R1: lane-parallel closed-form weights (2nd difference of prefix area).
// R2: bijective XCD swizzle (FETCH 212->57MB) + packed f32 FMA.
// R3: SOFTWARE-PIPELINED row loop. rocprof showed latency-limited (VALU 33%,
//     path ~62% of L2 ceiling, nothing pegged): the 8-load group was fully
//     drained before its FMAs, leaving no loads in flight during consume.
//     Now: prologue issues groups 0,1 BEFORE the weight VALU (weights hide
//     prologue latency); steady loop re-issues a group's loads right after
//     consuming it, keeping >=8 loads outstanding through every FMA phase.
//     Tail loop removed: each 64-row block is padded to a multiple of 8 rows
//     with index-clamped loads (uniform SALU min -> re-reads row kmax) and
//     Wl zeroed for lanes > kmax, so padded rows contribute exactly 0.
__global__ __launch_bounds__(256, 4) void roi_rows_kernel(
    const float* __restrict__ feat,       // [B, LV, D]
    const float* __restrict__ boxes,      // [N, 2]
    const int*   __restrict__ batch_idx,  // [N]
    const int*   __restrict__ order,      // [N] sorted by batch
    float*       __restrict__ out)        // [N, P, D]
{
    const int nwg = (N_ * P_) / 4;            // 16384 blocks
    const int cpx = nwg >> 3;                 // 2048 blocks per XCD chunk
    const int bid = blockIdx.x;
    const int swz = (bid & 7) * cpx + (bid >> 3);   // XCD k -> contiguous chunk k

    const int slot = (swz << 2) + (threadIdx.x >> 6);
    const int n    = order[slot >> 5];
    const int p    = slot & (P_ - 1);
    const int lane = threadIdx.x & 63;

    const float y1    = boxes[2 * n];
    const float y2    = boxes[2 * n + 1];
    const float bin_h = (y2 - y1) * (1.0f / (float)P_);
    const int   gh    = (int)ceilf(bin_h);

    const v4f* frow = (const v4f*)feat + (long)batch_idx[n] * (LV_ * (D_ / 4)) + lane;

    v4f acc = {0.f, 0.f, 0.f, 0.f};

    if (gh >= 1) {
        const float cntf    = (float)gh;
        const float sub     = bin_h / cntf;
        const float inv_sub = 1.0f / sub;                  // huge/inf ok: n clamped, NaN killed by fmaxf
        const float halfsub = 0.5f * sub;
        const float boff    = (y1 - 0.5f) + (float)p * bin_h;
        const float a       = fmaf(0.5f, sub, boff);       // first sample
        const float ylast   = fmaf(cntf - 0.5f, sub, boff);

        int r_first = (int)floorf(a);                      // a >= -0.5 so floor >= -1
        if (r_first < 0) r_first = 0;
        if (r_first > LV_ - 1) r_first = LV_ - 1;
        int r_last = (int)floorf(ylast) + 1;
        if (r_last > LV_ - 1) r_last = LV_ - 1;
        if (r_last < r_first) r_last = r_first;

        const float lanef = (float)lane;

        for (int base = r_first; base <= r_last; base += 64) {
            const int kmax = (r_last - base < 63) ? (r_last - base) : 63;  // valid 0..kmax
            const int m8   = (kmax + 8) & ~7;              // padded rows, multiple of 8
            const v4f* rp  = frow + (long)base * (D_ / 4);

            // clamped row load: padded rows re-read row kmax (weight 0)
#define LDI(kk, j) (rp[(long)((((kk) + (j)) > kmax) ? kmax : ((kk) + (j))) * (D_ / 4)])

            v4f a0, a1, a2, a3, a4, a5, a6, a7;
            v4f c0, c1, c2, c3, c4, c5, c6, c7;

#define LOAD8A(kk) do { a0=LDI(kk,0); a1=LDI(kk,1); a2=LDI(kk,2); a3=LDI(kk,3); \
                        a4=LDI(kk,4); a5=LDI(kk,5); a6=LDI(kk,6); a7=LDI(kk,7); } while (0)
#define LOAD8C(kk) do { c0=LDI(kk,0); c1=LDI(kk,1); c2=LDI(kk,2); c3=LDI(kk,3); \
                        c4=LDI(kk,4); c5=LDI(kk,5); c6=LDI(kk,6); c7=LDI(kk,7); } while (0)
#define FMA8A(kk) do { acc += a0 * lane_bcast_f(Wl, (kk) + 0); acc += a1 * lane_bcast_f(Wl, (kk) + 1); \
                       acc += a2 * lane_bcast_f(Wl, (kk) + 2); acc += a3 * lane_bcast_f(Wl, (kk) + 3); \
                       acc += a4 * lane_bcast_f(Wl, (kk) + 4); acc += a5 * lane_bcast_f(Wl, (kk) + 5); \
                       acc += a6 * lane_bcast_f(Wl, (kk) + 6); acc += a7 * lane_bcast_f(Wl, (kk) + 7); } while (0)
#define FMA8C(kk) do { acc += c0 * lane_bcast_f(Wl, (kk) + 0); acc += c1 * lane_bcast_f(Wl, (kk) + 1); \
                       acc += c2 * lane_bcast_f(Wl, (kk) + 2); acc += c3 * lane_bcast_f(Wl, (kk) + 3); \
                       acc += c4 * lane_bcast_f(Wl, (kk) + 4); acc += c5 * lane_bcast_f(Wl, (kk) + 5); \
                       acc += c6 * lane_bcast_f(Wl, (kk) + 6); acc += c7 * lane_bcast_f(Wl, (kk) + 7); } while (0)

            // ---- prologue: issue 2 groups before the weight VALU ----
            LOAD8A(0);
            if (m8 > 8) LOAD8C(8);

            // ---- lane-parallel weights (overlap prologue load latency) ----
            const int   r  = base + lane;
            const float d0 = ((float)base + lanef) - a;    // box-relative: good precision
            const float dm = d0 - 1.0f;
            const float dp = d0 + 1.0f;
            const float um = dm * inv_sub;
            const float u0 = d0 * inv_sub;
            const float up = dp * inv_sub;
            const float nm = fminf(fmaxf(ceilf(um), 0.0f), cntf);   // fmaxf eats NaN (0*inf)
            const float n0 = fminf(fmaxf(ceilf(u0), 0.0f), cntf);
            const float np = fminf(fmaxf(ceilf(up), 0.0f), cntf);
            float Pm = fmaf(nm, dm, -halfsub * fmaf(nm, nm, -nm));
            float P0 = fmaf(n0, d0, -halfsub * fmaf(n0, n0, -n0));
            float Pp = fmaf(np, dp, -halfsub * fmaf(np, np, -np));
            if (r == 0)       Pm = P0;                      // -> W(0) = P(1)-P(0)
            if (r == LV_ - 1) Pp = P0 + cntf;               // -> W(LV-1) = cnt + P(LV-2)-P(LV-1)
            float Wl = (Pm + Pp) - 2.0f * P0;
            Wl = (lane <= kmax) ? Wl : 0.0f;                // padded/garbage lanes -> weight 0

            // ---- steady: consume one group, immediately re-issue its loads ----
            int k = 0;
            for (;;) {
                FMA8A(k);
                if (k + 16 < m8) LOAD8A(k + 16);
                k += 8;
                if (k >= m8) break;
                FMA8C(k);
                if (k + 16 < m8) LOAD8C(k + 16);
                k += 8;
                if (k >= m8) break;
            }
#undef LDI
#undef LOAD8A
#undef LOAD8C
#undef FMA8A
#undef FMA8C
        }
    }

    const float inv_c = 1.0f / (float)(gh > 1 ? gh : 1);
    v4f res = acc * inv_c;
    v4f* op = (v4f*)out + ((long)n * P_ + p) * (D_ / 4) + lane;
    __builtin_nontemporal_store(res, op);
}

extern "C" void kernel_launch(void* const* d_in, const int* in_sizes, int n_in,
                              void* d_out, int out_size, void* d_ws, size_t ws_size,
                              hipStream_t stream) {
    const float* feat      = (const float*)d_in[0];
    const float* boxes     = (const float*)d_in[1];
    const int*   batch_idx = (const int*)d_in[2];
    float*       out       = (float*)d_out;
    int*         order     = (int*)d_ws;    // N_ ints

    build_order_kernel<<<1, 256, 0, stream>>>(batch_idx, order);
    roi_rows_kernel<<<(N_ * P_) / 4, 256, 0, stream>>>(feat, boxes, batch_idx, order, out);
}

// Round 4
// 192.451 us; speedup vs baseline: 1.0357x; 1.0357x over previous
//
#include <hip/hip_runtime.h>

#define B_  8
#define LV_ 4096
#define D_  256
#define N_  2048
#define P_  32

typedef float v4f __attribute__((ext_vector_type(4)));

__device__ __forceinline__ float lane_bcast_f(float v, int l) {
    return __int_as_float(__builtin_amdgcn_readlane(__float_as_int(v), l));
}

// Pass 1: counting-sort box ids by batch into order[] (d_ws) for XCD-L2 locality.
__global__ __launch_bounds__(256) void build_order_kernel(
    const int* __restrict__ batch_idx, int* __restrict__ order)
{
    __shared__ int cnt[B_], cur[B_];
    const int tid = threadIdx.x;
    if (tid < B_) cnt[tid] = 0;
    __syncthreads();
    for (int n = tid; n < N_; n += 256) atomicAdd(&cnt[batch_idx[n]], 1);
    __syncthreads();
    if (tid == 0) {
        int s = 0;
        for (int b = 0; b < B_; ++b) { cur[b] = s; s += cnt[b]; }
    }
    __syncthreads();
    for (int n = tid; n < N_; n += 256)
        order[atomicAdd(&cur[batch_idx[n]], 1)] = n;
}

// Pass 2: one wave per (box, bin), 4 waves per block.
//
// R1: lane-parallel closed-form weights (2nd difference of prefix area).
// R2: bijective XCD swizzle (FETCH 212->57MB) + packed f32 FMA.      [124us]
// R3: FAILED (133us): clamp-indexed loads added ~3-4 VALU/load (VALU 54%)
//     and launch_bounds(,4) halved occupancy (37%). Pipeline idea untested.
// R4: R2 + double-buffered 4-row groups with STATIC addressing only:
//     - all loads imm-offset (rows 0..7 * 1KB = 0..7168B, fits 13-bit imm)
//       from one per-wave pointer advanced 8 rows/iter (2 VALU / 8 rows);
//     - prologue loads A,B before the weight VALU (weights hide latency);
//     - steady loop re-issues a group right after consuming it, so >=4
//       loads stay outstanding through every FMA phase (R2 drained to 0);
//     - tail <=3 rows via simple per-row loop, wave-uniform branches;
//     - VGPR target ~60 (8 v4f buffers + acc + addr) -> 64-VGPR occupancy
//       tier; NO launch_bounds min-waves clause (R3's occupancy mistake).
__global__ __launch_bounds__(256) void roi_rows_kernel(
    const float* __restrict__ feat,       // [B, LV, D]
    const float* __restrict__ boxes,      // [N, 2]
    const int*   __restrict__ batch_idx,  // [N]
    const int*   __restrict__ order,      // [N] sorted by batch
    float*       __restrict__ out)        // [N, P, D]
{
    const int nwg = (N_ * P_) / 4;            // 16384 blocks
    const int cpx = nwg >> 3;                 // 2048 blocks per XCD chunk
    const int bid = blockIdx.x;
    const int swz = (bid & 7) * cpx + (bid >> 3);   // XCD k -> contiguous chunk k

    const int slot = (swz << 2) + (threadIdx.x >> 6);
    const int n    = order[slot >> 5];
    const int p    = slot & (P_ - 1);
    const int lane = threadIdx.x & 63;

    const float y1    = boxes[2 * n];
    const float y2    = boxes[2 * n + 1];
    const float bin_h = (y2 - y1) * (1.0f / (float)P_);
    const int   gh    = (int)ceilf(bin_h);

    const v4f* frow = (const v4f*)feat + (long)batch_idx[n] * (LV_ * (D_ / 4)) + lane;

    v4f acc = {0.f, 0.f, 0.f, 0.f};

    if (gh >= 1) {
        const float cntf    = (float)gh;
        const float sub     = bin_h / cntf;
        const float inv_sub = 1.0f / sub;                  // huge/inf ok: n clamped, NaN killed by fmaxf
        const float halfsub = 0.5f * sub;
        const float boff    = (y1 - 0.5f) + (float)p * bin_h;
        const float a       = fmaf(0.5f, sub, boff);       // first sample
        const float ylast   = fmaf(cntf - 0.5f, sub, boff);

        int r_first = (int)floorf(a);                      // a >= -0.5 so floor >= -1
        if (r_first < 0) r_first = 0;
        if (r_first > LV_ - 1) r_first = LV_ - 1;
        int r_last = (int)floorf(ylast) + 1;
        if (r_last > LV_ - 1) r_last = LV_ - 1;
        if (r_last < r_first) r_last = r_first;

        const float lanef = (float)lane;

        for (int base = r_first; base <= r_last; base += 64) {
            const int kmax = (r_last - base < 63) ? (r_last - base) : 63;  // valid 0..kmax
            const int full = (kmax + 1) & ~3;              // rows covered by 4-row groups
            const v4f* rp  = frow + (long)base * (D_ / 4);

            v4f A0, A1, A2, A3, B0, B1, B2, B3;

            // ---- prologue: issue up to 2 groups before the weight VALU ----
            if (full >= 4) { A0 = rp[0];   A1 = rp[64];  A2 = rp[128]; A3 = rp[192]; }
            if (full >= 8) { B0 = rp[256]; B1 = rp[320]; B2 = rp[384]; B3 = rp[448]; }

            // ---- lane-parallel weights (overlap prologue load latency) ----
            const int   r  = base + lane;
            const float d0 = ((float)base + lanef) - a;    // box-relative: good precision
            const float dm = d0 - 1.0f;
            const float dp = d0 + 1.0f;
            const float um = dm * inv_sub;
            const float u0 = d0 * inv_sub;
            const float up = dp * inv_sub;
            const float nm = fminf(fmaxf(ceilf(um), 0.0f), cntf);   // fmaxf eats NaN (0*inf)
            const float n0 = fminf(fmaxf(ceilf(u0), 0.0f), cntf);
            const float np = fminf(fmaxf(ceilf(up), 0.0f), cntf);
            float Pm = fmaf(nm, dm, -halfsub * fmaf(nm, nm, -nm));
            float P0 = fmaf(n0, d0, -halfsub * fmaf(n0, n0, -n0));
            float Pp = fmaf(np, dp, -halfsub * fmaf(np, np, -np));
            if (r == 0)       Pm = P0;                      // -> W(0) = P(1)-P(0)
            if (r == LV_ - 1) Pp = P0 + cntf;               // -> W(LV-1) = cnt + P(LV-2)-P(LV-1)
            const float Wl = (Pm + Pp) - 2.0f * P0;
            // lanes with r > kmax hold garbage W; never read (readlane idx <= kmax)

            // ---- steady: consume a group, immediately re-issue its next loads ----
            const v4f* q = rp + 512;                        // row base+8, per-wave ptr
            int k = 0;
            while (k + 8 <= full) {
                acc += A0 * lane_bcast_f(Wl, k + 0);
                acc += A1 * lane_bcast_f(Wl, k + 1);
                acc += A2 * lane_bcast_f(Wl, k + 2);
                acc += A3 * lane_bcast_f(Wl, k + 3);
                if (k + 12 <= full) { A0 = q[0];   A1 = q[64];  A2 = q[128]; A3 = q[192]; }
                acc += B0 * lane_bcast_f(Wl, k + 4);
                acc += B1 * lane_bcast_f(Wl, k + 5);
                acc += B2 * lane_bcast_f(Wl, k + 6);
                acc += B3 * lane_bcast_f(Wl, k + 7);
                if (k + 16 <= full) { B0 = q[256]; B1 = q[320]; B2 = q[384]; B3 = q[448]; }
                q += 512; k += 8;
            }
            if (k < full) {                                 // leftover 4-group sits in A
                acc += A0 * lane_bcast_f(Wl, k + 0);
                acc += A1 * lane_bcast_f(Wl, k + 1);
                acc += A2 * lane_bcast_f(Wl, k + 2);
                acc += A3 * lane_bcast_f(Wl, k + 3);
                k += 4;
            }
            for (; k <= kmax; ++k) {                        // tail <= 3 rows
                const v4f v = rp[(long)k * (D_ / 4)];
                acc += v * lane_bcast_f(Wl, k);
            }
        }
    }

    const float inv_c = 1.0f / (float)(gh > 1 ? gh : 1);
    v4f res = acc * inv_c;
    v4f* op = (v4f*)out + ((long)n * P_ + p) * (D_ / 4) + lane;
    __builtin_nontemporal_store(res, op);
}

extern "C" void kernel_launch(void* const* d_in, const int* in_sizes, int n_in,
                              void* d_out, int out_size, void* d_ws, size_t ws_size,
                              hipStream_t stream) {
    const float* feat      = (const float*)d_in[0];
    const float* boxes     = (const float*)d_in[1];
    const int*   batch_idx = (const int*)d_in[2];
    float*       out       = (float*)d_out;
    int*         order     = (int*)d_ws;    // N_ ints

    build_order_kernel<<<1, 256, 0, stream>>>(batch_idx, order);
    roi_rows_kernel<<<(N_ * P_) / 4, 256, 0, stream>>>(feat, boxes, batch_idx, order, out);
}